// Round 9
// baseline (196.480 us; speedup 1.0000x reference)
//
#include <hip/hip_runtime.h>
#include <hip/hip_fp16.h>

#define HID 64
#define ELLK 32   // slots/node; kept degree ~Poisson(5.5), max over 100k ~18
#define CUT_D2 132.5471f   // drop rbf < 1e-5 (R10: measured no absmax change)

typedef _Float16 half8 __attribute__((ext_vector_type(8)));
typedef float f32x4 __attribute__((ext_vector_type(4)));

__device__ __forceinline__ float rbf_of(unsigned w) {
    return __half2float(__ushort_as_half((unsigned short)(w & 0x7fff)));
}

// x16[n][h] = fp16(emb[z[n]][h]); also zeroes ELL counters (rides this kernel).
__global__ void embed_kernel(const int* __restrict__ z, const float* __restrict__ emb,
                             __half* __restrict__ x16, int* __restrict__ cnt, int n) {
    int t = blockIdx.x * blockDim.x + threadIdx.x;
    if (t <= n) cnt[t] = 0;
    if (t >= n * HID / 2) return;
    int node = t >> 5, h2 = (t & 31) * 2;
    const float* src = emb + z[node] * HID + h2;
    __half2 v;
    v.x = __float2half(src[0]);
    v.y = __float2half(src[1]);
    *(__half2*)(x16 + (size_t)node * HID + h2) = v;
}

// ELL fill + fused rbf for KEPT edges; packed record (col<<15)|fp16(rbf).
__global__ void fill_kernel(const int* __restrict__ row, const int* __restrict__ col,
                            const float* __restrict__ pos, int* __restrict__ cnt,
                            unsigned* __restrict__ ell, int e) {
    int t = blockIdx.x * blockDim.x + threadIdx.x;
    if (t >= e) return;
    int r = row[t], c = col[t];
    float dx = pos[3 * r]     - pos[3 * c];
    float dy = pos[3 * r + 1] - pos[3 * c + 1];
    float dz = pos[3 * r + 2] - pos[3 * c + 2];
    float d2 = dx * dx + dy * dy + dz * dz;
    if (d2 > CUT_D2) return;
    float rbf = expf(-sqrtf(d2));
    unsigned short hb = __half_as_ushort(__float2half(rbf));
    int p = atomicAdd(&cnt[r], 1);
    if (p < ELLK) ell[(size_t)r * ELLK + p] = ((unsigned)c << 15) | (unsigned)hb;
}

// R26: R25 wave-specialized fused layer + PREDICATED dead-slot loads.
// R25 request accounting: pack-uniform r-block guard (8r < mcT, mcT=max of 8
// counts) issues ~102 rows/pack vs ~44 useful -> ~57% dead row-loads; dead
// targets (own row) thrash out of L1 under 32 streaming waves -> real L2/L3
// requests. R26: `slot < c_own` is UNIFORM within each 8-lane group -> a
// divergent if around the load exec-masks whole octets: masked lanes issue
// ZERO requests. R19's serialization trap (load;fma pairs forcing vmcnt(0))
// avoided by two-phase r-blocks: phase A = 8 predicated loads ONLY into v[8]
// (zero-init for NaN-safety of dead lanes); phase B = 8 unconditional FMA
// groups (rbf via a second shfl of the pre-masked rec -> no extra live regs).
// Dead slots: f=0 AND v=0 -> exact no-ops; FMA order/rounding unchanged ->
// bit-identical (absmax 0.00390625). Regs: v 32 + acc 8 + rec 4 + misc ~58 < 64.
__global__ void __launch_bounds__(512)
layer_kernel(const __half* __restrict__ x16, const int* __restrict__ cnt,
             const unsigned* __restrict__ ell,
             const float* __restrict__ W, const float* __restrict__ b,
             float* __restrict__ out32, __half* __restrict__ out16, int n) {
    __shared__ __align__(16) __half ltile[4][16 * HID];   // 8KB: 4 tiles
    __shared__ __align__(16) __half wlds[8][64][8];       // 8KB: [frag][lane][8 halves]
    int tid = threadIdx.x;
    int lane = tid & 63;
    int wv = tid >> 6;                 // wave 0..7

    int grp = lane >> 3;               // gather: group = node within the pack
    int gl  = lane & 7;                // gather: lane within group = h-chunk
    int r16 = lane & 15;               // mfma: A row / out col
    int quad = lane >> 4;              // mfma: k-chunk / out row group

    // ---- W -> LDS preload (512 threads, 512 frag-slots, 1 each) ----
    {
        int f = tid >> 6, l = tid & 63;
        int ht = f >> 1, kt = f & 1, q = l >> 4, r = l & 15;
        const float* src = W + (ht * 16 + r) * HID + kt * 32 + q * 8;
        half8 h;
#pragma unroll
        for (int j = 0; j < 8; ++j) h[j] = (_Float16)src[j];
        *(half8*)&wlds[f][l][0] = h;
    }
    float biasv[4];
#pragma unroll
    for (int ht = 0; ht < 4; ++ht) biasv[ht] = b[ht * 16 + r16];
    __syncthreads();

    int ntiles = (n + 15) >> 4;
    int Tb = blockIdx.x << 2;          // first tile of this block

    // ================= gather phase: one 8-node pack per wave =================
    {
        int n8 = (Tb << 4) + (wv << 3);                    // pack base node
        int own = n8 + grp; if (own >= n) own = n - 1;     // clamp (loads only)

        int cn = n8 + (lane & 7);
        int myc = cnt[cn < n ? cn : n - 1];
        if (cn >= n) myc = 0;
        if (myc > ELLK) myc = ELLK;

        unsigned rec[4];
#pragma unroll
        for (int r = 0; r < 4; ++r)
            rec[r] = ell[(size_t)own * ELLK + r * 8 + gl];

        half8 res = *(const half8*)(x16 + (size_t)own * HID + gl * 8);

        int m = myc;
        m = max(m, __shfl_xor(m, 1));
        m = max(m, __shfl_xor(m, 2));
        m = max(m, __shfl_xor(m, 4));
        int mcT = __builtin_amdgcn_readfirstlane(m);

        int c_own = __shfl(myc, grp);                      // uniform within group
#pragma unroll
        for (int r = 0; r < 4; ++r)
            if (r * 8 + gl >= c_own) rec[r] = (unsigned)own << 15;  // rbf=0 no-op

        float acc[8];
#pragma unroll
        for (int k = 0; k < 8; ++k) acc[k] = (float)res[k];

#pragma unroll
        for (int r = 0; r < 4; ++r) {
            if (8 * r < mcT) {                         // wave-uniform coarse guard
                half8 v[8];
                // phase A: predicated loads ONLY (masked octets request nothing)
#pragma unroll
                for (int i = 0; i < 8; ++i) {
#pragma unroll
                    for (int k = 0; k < 8; ++k) v[i][k] = (_Float16)0.f;
                    if (r * 8 + i < c_own) {           // group-uniform divergence
                        unsigned w = __shfl(rec[r], (lane & 56) + i);
                        v[i] = *(const half8*)(x16 + (size_t)(w >> 15) * HID + gl * 8);
                    }
                }
                // phase B: unconditional FMAs; f from pre-masked rec (0 if dead)
#pragma unroll
                for (int i = 0; i < 8; ++i) {
                    unsigned w = __shfl(rec[r], (lane & 56) + i);
                    float f = rbf_of(w);
#pragma unroll
                    for (int k = 0; k < 8; ++k)
                        acc[k] = fmaf((float)v[i][k], f, acc[k]);
                }
            }
        }

        half8 o;
#pragma unroll
        for (int k = 0; k < 8; ++k) o[k] = (_Float16)acc[k];
        // wave wv -> tile wv/2, rows (wv&1)*8+grp; swizzled (R23 layout)
        char* tile = (char*)&ltile[wv >> 1][0];
        int ni = ((wv & 1) << 3) + grp;
        *(half8*)(tile + ni * 128 + ((gl << 4) ^ ((ni & 7) << 4))) = o;
    }
    __syncthreads();

    // ================= mfma phase: wave w -> tile (w&3), ht-half (w>>2) =======
    {
        int tw = wv & 3;
        int t = Tb + tw;
        if (t < ntiles) {
            int tbase = t << 4;
            char* tile = (char*)&ltile[tw][0];
            const half8* wl = (const half8*)&wlds[0][0][0];
            half8 afrag0 = *(const half8*)(tile + r16 * 128 + ((quad << 4) ^ ((r16 & 7) << 4)));
            half8 afrag1 = *(const half8*)(tile + r16 * 128 + (((quad + 4) << 4) ^ ((r16 & 7) << 4)));
            int htb = (wv >> 2) << 1;                  // 0 or 2
#pragma unroll
            for (int hh = 0; hh < 2; ++hh) {
                int ht = htb + hh;
                f32x4 acc = {biasv[ht], biasv[ht], biasv[ht], biasv[ht]};
                half8 b0 = wl[(ht * 2 + 0) * 64 + lane];   // stride-1 ds_read_b128
                half8 b1 = wl[(ht * 2 + 1) * 64 + lane];
                acc = __builtin_amdgcn_mfma_f32_16x16x32_f16(afrag0, b0, acc, 0, 0, 0);
                acc = __builtin_amdgcn_mfma_f32_16x16x32_f16(afrag1, b1, acc, 0, 0, 0);
#pragma unroll
                for (int r = 0; r < 4; ++r) {
                    int row = tbase + quad * 4 + r;
                    if (row < n) {                     // guards garbage tail rows too
                        float v = fmaxf(acc[r], 0.0f);
                        size_t idx = (size_t)row * HID + ht * 16 + r16;
                        if (out32) out32[idx] = v;
                        if (out16) out16[idx] = __float2half(v);
                    }
                }
            }
        }
    }
}

extern "C" void kernel_launch(void* const* d_in, const int* in_sizes, int n_in,
                              void* d_out, int out_size, void* d_ws, size_t ws_size,
                              hipStream_t stream) {
    const int*   z    = (const int*)d_in[0];
    const float* pos  = (const float*)d_in[1];
    const int*   eidx = (const int*)d_in[2];
    const float* emb  = (const float*)d_in[3];
    const float* Ws   = (const float*)d_in[4];
    const float* bs   = (const float*)d_in[5];
    int n = in_sizes[0];
    int e = in_sizes[2] / 2;
    int nlayers = in_sizes[4] / (HID * HID);
    const int* row = eidx;
    const int* col = eidx + e;
    float* out = (float*)d_out;

    char* ws = (char*)d_ws;
    __half*   X16 = (__half*)ws;                                   // n*64 fp16 (12.8 MB)
    __half*   Y16 = X16 + (size_t)n * HID;                         // n*64 fp16 (ping-pong)
    unsigned* ell = (unsigned*)((char*)Y16 + (size_t)n * HID * 2); // (n+2)*ELLK u32
    int*      cnt = (int*)((char*)ell + (size_t)(n + 2) * ELLK * 4); // n+1 ints

    // 5 dispatches: embed(+cnt zero), fill, 3x fused layer (wave-specialized)
    // (R16 lesson: hipLaunchCooperativeKernel does NOT survive this harness's
    // graph capture — remaining ~4 dispatch gaps are structural.)
    embed_kernel<<<(n * HID / 2 + 255) / 256, 256, 0, stream>>>(z, emb, X16, cnt, n);
    fill_kernel<<<(e + 255) / 256, 256, 0, stream>>>(row, col, pos, cnt, ell, e);

    int ntiles = (n + 15) >> 4;
    int lblocks = (ntiles + 3) >> 2;   // 4 tiles/block (8 waves: 8 packs)
    for (int l = 0; l < nlayers; ++l) {
        bool last = (l == nlayers - 1);
        const __half* src = (l & 1) ? Y16 : X16;   // ping-pong: fused kernel reads
        __half*       dst = (l & 1) ? X16 : Y16;   // src everywhere while writing dst
        layer_kernel<<<lblocks, 512, 0, stream>>>(src, cnt, ell,
                                                  Ws + (size_t)l * HID * HID,
                                                  bs + (size_t)l * HID,
                                                  last ? out : nullptr,
                                                  last ? nullptr : dst, n);
    }
}

// Round 10
// 176.742 us; speedup vs baseline: 1.1117x; 1.1117x over previous
//
#include <hip/hip_runtime.h>
#include <hip/hip_fp16.h>

#define HID 64
#define ELLK 32   // slots/node; kept degree ~Poisson(5.5), max over 100k ~18
#define CUT_D2 132.5471f   // drop rbf < 1e-5 (R10: measured no absmax change)

typedef _Float16 half8 __attribute__((ext_vector_type(8)));
typedef float f32x4 __attribute__((ext_vector_type(4)));

__device__ __forceinline__ float rbf_of(unsigned w) {
    return __half2float(__ushort_as_half((unsigned short)(w & 0x7fff)));
}

// x16[n][h] = fp16(emb[z[n]][h]); also zeroes ELL counters (rides this kernel).
__global__ void embed_kernel(const int* __restrict__ z, const float* __restrict__ emb,
                             __half* __restrict__ x16, int* __restrict__ cnt, int n) {
    int t = blockIdx.x * blockDim.x + threadIdx.x;
    if (t <= n) cnt[t] = 0;
    if (t >= n * HID / 2) return;
    int node = t >> 5, h2 = (t & 31) * 2;
    const float* src = emb + z[node] * HID + h2;
    __half2 v;
    v.x = __float2half(src[0]);
    v.y = __float2half(src[1]);
    *(__half2*)(x16 + (size_t)node * HID + h2) = v;
}

// ELL fill + fused rbf for KEPT edges; packed record (col<<15)|fp16(rbf).
__global__ void fill_kernel(const int* __restrict__ row, const int* __restrict__ col,
                            const float* __restrict__ pos, int* __restrict__ cnt,
                            unsigned* __restrict__ ell, int e) {
    int t = blockIdx.x * blockDim.x + threadIdx.x;
    if (t >= e) return;
    int r = row[t], c = col[t];
    float dx = pos[3 * r]     - pos[3 * c];
    float dy = pos[3 * r + 1] - pos[3 * c + 1];
    float dz = pos[3 * r + 2] - pos[3 * c + 2];
    float d2 = dx * dx + dy * dy + dz * dz;
    if (d2 > CUT_D2) return;
    float rbf = expf(-sqrtf(d2));
    unsigned short hb = __half_as_ushort(__float2half(rbf));
    int p = atomicAdd(&cnt[r], 1);
    if (p < ELLK) ell[(size_t)r * ELLK + p] = ((unsigned)c << 15) | (unsigned)hb;
}

// R27: R25 wave-specialized fused layer + OCTET-GRANULAR dead-load skip.
// R26 post-mortem (+20us): per-slot predication = 8 exec toggles + 32 movs +
// 8 extra shfls per r-block — codegen tax ran on every octet, loss. R27 keeps
// the R25 body VERBATIM and changes only the r-block guard: mcT (pack max) ->
// c_own (group count). `8r < c_own` is UNIFORM within each 8-lane group, so
// it's ONE divergent branch wrapping the unchanged 8-load+8-FMA octet body:
// dead octets issue zero requests, one exec toggle, no extra instructions.
// Partial octets still load fully; their dead slots are pre-masked rbf=0
// exact no-ops -> skipped FMAs are identities -> bit-identical (0.00390625).
// shfl inside divergence is safe: ds_bpermute reads the register file of the
// source lane regardless of exec. E[octets/node] 1.6 -> ~1.11 (-30% requests).
__global__ void __launch_bounds__(512)
layer_kernel(const __half* __restrict__ x16, const int* __restrict__ cnt,
             const unsigned* __restrict__ ell,
             const float* __restrict__ W, const float* __restrict__ b,
             float* __restrict__ out32, __half* __restrict__ out16, int n) {
    __shared__ __align__(16) __half ltile[4][16 * HID];   // 8KB: 4 tiles
    __shared__ __align__(16) __half wlds[8][64][8];       // 8KB: [frag][lane][8 halves]
    int tid = threadIdx.x;
    int lane = tid & 63;
    int wv = tid >> 6;                 // wave 0..7

    int grp = lane >> 3;               // gather: group = node within the pack
    int gl  = lane & 7;                // gather: lane within group = h-chunk
    int r16 = lane & 15;               // mfma: A row / out col
    int quad = lane >> 4;              // mfma: k-chunk / out row group

    // ---- W -> LDS preload (512 threads, 512 frag-slots, 1 each) ----
    {
        int f = tid >> 6, l = tid & 63;
        int ht = f >> 1, kt = f & 1, q = l >> 4, r = l & 15;
        const float* src = W + (ht * 16 + r) * HID + kt * 32 + q * 8;
        half8 h;
#pragma unroll
        for (int j = 0; j < 8; ++j) h[j] = (_Float16)src[j];
        *(half8*)&wlds[f][l][0] = h;
    }
    float biasv[4];
#pragma unroll
    for (int ht = 0; ht < 4; ++ht) biasv[ht] = b[ht * 16 + r16];
    __syncthreads();

    int ntiles = (n + 15) >> 4;
    int Tb = blockIdx.x << 2;          // first tile of this block

    // ================= gather phase: one 8-node pack per wave =================
    {
        int n8 = (Tb << 4) + (wv << 3);                    // pack base node
        int own = n8 + grp; if (own >= n) own = n - 1;     // clamp (loads only)

        int cn = n8 + (lane & 7);
        int myc = cnt[cn < n ? cn : n - 1];
        if (cn >= n) myc = 0;
        if (myc > ELLK) myc = ELLK;

        unsigned rec[4];
#pragma unroll
        for (int r = 0; r < 4; ++r)
            rec[r] = ell[(size_t)own * ELLK + r * 8 + gl];

        half8 res = *(const half8*)(x16 + (size_t)own * HID + gl * 8);

        int c_own = __shfl(myc, grp);                      // uniform within group
#pragma unroll
        for (int r = 0; r < 4; ++r)
            if (r * 8 + gl >= c_own) rec[r] = (unsigned)own << 15;  // rbf=0 no-op

        float acc[8];
#pragma unroll
        for (int k = 0; k < 8; ++k) acc[k] = (float)res[k];

#pragma unroll
        for (int r = 0; r < 4; ++r) {
            if (8 * r < c_own) {                       // group-uniform octet guard
#pragma unroll
                for (int i = 0; i < 8; ++i) {
                    unsigned w = __shfl(rec[r], (lane & 56) + i);
                    half8 v = *(const half8*)(x16 + (size_t)(w >> 15) * HID + gl * 8);
                    float f = rbf_of(w);               // pre-masked: 0 if dead
#pragma unroll
                    for (int k = 0; k < 8; ++k)
                        acc[k] = fmaf((float)v[k], f, acc[k]);
                }
            }
        }

        half8 o;
#pragma unroll
        for (int k = 0; k < 8; ++k) o[k] = (_Float16)acc[k];
        // wave wv -> tile wv/2, rows (wv&1)*8+grp; swizzled (R23 layout)
        char* tile = (char*)&ltile[wv >> 1][0];
        int ni = ((wv & 1) << 3) + grp;
        *(half8*)(tile + ni * 128 + ((gl << 4) ^ ((ni & 7) << 4))) = o;
    }
    __syncthreads();

    // ================= mfma phase: wave w -> tile (w&3), ht-half (w>>2) =======
    {
        int tw = wv & 3;
        int t = Tb + tw;
        if (t < ntiles) {
            int tbase = t << 4;
            char* tile = (char*)&ltile[tw][0];
            const half8* wl = (const half8*)&wlds[0][0][0];
            half8 afrag0 = *(const half8*)(tile + r16 * 128 + ((quad << 4) ^ ((r16 & 7) << 4)));
            half8 afrag1 = *(const half8*)(tile + r16 * 128 + (((quad + 4) << 4) ^ ((r16 & 7) << 4)));
            int htb = (wv >> 2) << 1;                  // 0 or 2
#pragma unroll
            for (int hh = 0; hh < 2; ++hh) {
                int ht = htb + hh;
                f32x4 acc = {biasv[ht], biasv[ht], biasv[ht], biasv[ht]};
                half8 b0 = wl[(ht * 2 + 0) * 64 + lane];   // stride-1 ds_read_b128
                half8 b1 = wl[(ht * 2 + 1) * 64 + lane];
                acc = __builtin_amdgcn_mfma_f32_16x16x32_f16(afrag0, b0, acc, 0, 0, 0);
                acc = __builtin_amdgcn_mfma_f32_16x16x32_f16(afrag1, b1, acc, 0, 0, 0);
#pragma unroll
                for (int r = 0; r < 4; ++r) {
                    int row = tbase + quad * 4 + r;
                    if (row < n) {                     // guards garbage tail rows too
                        float v = fmaxf(acc[r], 0.0f);
                        size_t idx = (size_t)row * HID + ht * 16 + r16;
                        if (out32) out32[idx] = v;
                        if (out16) out16[idx] = __float2half(v);
                    }
                }
            }
        }
    }
}

extern "C" void kernel_launch(void* const* d_in, const int* in_sizes, int n_in,
                              void* d_out, int out_size, void* d_ws, size_t ws_size,
                              hipStream_t stream) {
    const int*   z    = (const int*)d_in[0];
    const float* pos  = (const float*)d_in[1];
    const int*   eidx = (const int*)d_in[2];
    const float* emb  = (const float*)d_in[3];
    const float* Ws   = (const float*)d_in[4];
    const float* bs   = (const float*)d_in[5];
    int n = in_sizes[0];
    int e = in_sizes[2] / 2;
    int nlayers = in_sizes[4] / (HID * HID);
    const int* row = eidx;
    const int* col = eidx + e;
    float* out = (float*)d_out;

    char* ws = (char*)d_ws;
    __half*   X16 = (__half*)ws;                                   // n*64 fp16 (12.8 MB)
    __half*   Y16 = X16 + (size_t)n * HID;                         // n*64 fp16 (ping-pong)
    unsigned* ell = (unsigned*)((char*)Y16 + (size_t)n * HID * 2); // (n+2)*ELLK u32
    int*      cnt = (int*)((char*)ell + (size_t)(n + 2) * ELLK * 4); // n+1 ints

    // 5 dispatches: embed(+cnt zero), fill, 3x fused layer (wave-specialized)
    // (R16 lesson: hipLaunchCooperativeKernel does NOT survive this harness's
    // graph capture — remaining ~4 dispatch gaps are structural.)
    embed_kernel<<<(n * HID / 2 + 255) / 256, 256, 0, stream>>>(z, emb, X16, cnt, n);
    fill_kernel<<<(e + 255) / 256, 256, 0, stream>>>(row, col, pos, cnt, ell, e);

    int ntiles = (n + 15) >> 4;
    int lblocks = (ntiles + 3) >> 2;   // 4 tiles/block (8 waves: 8 packs)
    for (int l = 0; l < nlayers; ++l) {
        bool last = (l == nlayers - 1);
        const __half* src = (l & 1) ? Y16 : X16;   // ping-pong: fused kernel reads
        __half*       dst = (l & 1) ? X16 : Y16;   // src everywhere while writing dst
        layer_kernel<<<lblocks, 512, 0, stream>>>(src, cnt, ell,
                                                  Ws + (size_t)l * HID * HID,
                                                  bs + (size_t)l * HID,
                                                  last ? out : nullptr,
                                                  last ? nullptr : dst, n);
    }
}